// Round 1
// 233.153 us; speedup vs baseline: 1.2361x; 1.2361x over previous
//
#include <hip/hip_runtime.h>
#include <hip/hip_bf16.h>
#include <math.h>

// GAT x3 + LayerNorm for MI355X (gfx950).
// R12: CSR build collapsed into a bucketed scatter (CAP=64 slots/node) done
// inside k1's histogram pass (pos = atomicAdd(deg[d])) -> scan_kernel and
// fill_kernel eliminated. Per-edge softmax weights are computed INLINE in the
// aggregation kernels from {src, eattr} records + an al_s gather (f32, no
// fp16 rounding) -> ew4/ew4/ew1 kernels eliminated. Self-loops are handled
// analytically per node (no materialized record). 11 dispatches -> 6.
// Carried: bf16 h, al = A @ va via extra MFMA col-tile, layer-0
// aggregate-then-project, scalar-path (s_load) edge-record reads.

typedef __attribute__((ext_vector_type(8))) short short8;
typedef __attribute__((ext_vector_type(4))) float float4v;

#define CAP 64

__device__ __forceinline__ float wave_sum(float v) {
#pragma unroll
  for (int off = 32; off > 0; off >>= 1) v += __shfl_xor(v, off, 64);
  return v;
}

__device__ __forceinline__ unsigned short f2bf(float v) {
  unsigned u = __float_as_uint(v);
  unsigned r = u + 0x7fff + ((u >> 16) & 1);  // RNE
  return (unsigned short)(r >> 16);
}

__device__ __forceinline__ float bf2f(unsigned short u) {
  return __uint_as_float(((unsigned)u) << 16);
}

// ---------------- K1 mega-dispatch ----------------
// blocks [0,272): Wf1 tiles; [272,352): Wf2 tiles; 352: wedot;
// [353,353+gD): layer-0 al dots; rest: degree histogram + bucket scatter.
__global__ __launch_bounds__(256) void k1_kernel(
    const float* __restrict__ x, const int* __restrict__ srcv, const int* __restrict__ dstv,
    const float* __restrict__ eattr,
    const float* __restrict__ W0, const float* __restrict__ as0, const float* __restrict__ ad0,
    const float* __restrict__ We0, const float* __restrict__ ae0,
    const float* __restrict__ W1, const float* __restrict__ as1, const float* __restrict__ ad1,
    const float* __restrict__ We1, const float* __restrict__ ae1,
    const float* __restrict__ W2, const float* __restrict__ as2, const float* __restrict__ ad2,
    const float* __restrict__ We2, const float* __restrict__ ae2,
    unsigned short* __restrict__ Wf1, unsigned short* __restrict__ Wf2,
    float* __restrict__ wedot, float* __restrict__ al_s, float* __restrict__ al_d,
    int* __restrict__ deg, float* __restrict__ asum, int2* __restrict__ ebuf,
    int N, int E, int gD) {
  int b = blockIdx.x;
  int tid = threadIdx.x;
  if (b < 272) {  // Wf1: 16 W1-tiles + 1 va1 tile, bf16 fragment order
    int idx = b * 256 + tid;
    int j = idx & 7, lane = (idx >> 3) & 63, ks = (idx >> 9) & 7, nt = idx >> 12;
    int k = ks * 32 + (lane >> 4) * 8 + j;
    int col = lane & 15;
    float v = 0.f;
    if (nt < 16) {
      v = W1[(size_t)k * 256 + nt * 16 + col];
    } else if (col < 4) {
      for (int c = 0; c < 64; c++) v = fmaf(W1[(size_t)k * 256 + col * 64 + c], as1[col * 64 + c], v);
    } else if (col < 8) {
      int h = col - 4;
      for (int c = 0; c < 64; c++) v = fmaf(W1[(size_t)k * 256 + h * 64 + c], ad1[h * 64 + c], v);
    }
    Wf1[idx] = f2bf(v);
  } else if (b < 352) {  // Wf2: 4 W2-tiles + 1 va2 tile
    int idx = (b - 272) * 256 + tid;
    int j = idx & 7, lane = (idx >> 3) & 63, ks = (idx >> 9) & 7, nt = idx >> 12;
    int k = ks * 32 + (lane >> 4) * 8 + j;
    int col = lane & 15;
    float v = 0.f;
    if (nt < 4) {
      v = W2[(size_t)k * 64 + nt * 16 + col];
    } else if (col < 1) {
      for (int c = 0; c < 64; c++) v = fmaf(W2[(size_t)k * 64 + c], as2[c], v);
    } else if (col < 2) {
      for (int c = 0; c < 64; c++) v = fmaf(W2[(size_t)k * 64 + c], ad2[c], v);
    }
    Wf2[idx] = f2bf(v);
  } else if (b == 352) {  // wedot
    if (tid >= 64) return;
    int c = tid;
    for (int h = 0; h < 4; h++) {
      float v = wave_sum(We0[h * 64 + c] * ae0[h * 64 + c]);
      if (c == 0) wedot[h] = v;
    }
    for (int h = 0; h < 4; h++) {
      float v = wave_sum(We1[h * 64 + c] * ae1[h * 64 + c]);
      if (c == 0) wedot[4 + h] = v;
    }
    float v = wave_sum(We2[c] * ae2[c]);
    if (c == 0) wedot[8] = v;
  } else if (b < 353 + gD) {  // layer-0 dots: al = x @ va0
    __shared__ float va[128];
    if (tid < 128) {
      int k = tid >> 3, col = tid & 7;
      float v = 0.f;
      if (col < 4) {
        for (int c = 0; c < 64; c++) v = fmaf(W0[(size_t)k * 256 + col * 64 + c], as0[col * 64 + c], v);
      } else {
        int h = col - 4;
        for (int c = 0; c < 64; c++) v = fmaf(W0[(size_t)k * 256 + h * 64 + c], ad0[h * 64 + c], v);
      }
      va[tid] = v;
    }
    __syncthreads();
    int node = (b - 353) * 256 + tid;
    if (node >= N) return;
    const float4* xr = (const float4*)(x + (size_t)node * 16);
    float4 xv[4];
#pragma unroll
    for (int q = 0; q < 4; q++) xv[q] = xr[q];
    float al[8];
#pragma unroll
    for (int j = 0; j < 8; j++) al[j] = 0.f;
#pragma unroll
    for (int k = 0; k < 16; k++) {
      float xk = ((const float*)xv)[k];
#pragma unroll
      for (int j = 0; j < 8; j++) al[j] = fmaf(xk, va[k * 8 + j], al[j]);
    }
    ((float4*)al_s)[node] = make_float4(al[0], al[1], al[2], al[3]);
    ((float4*)al_d)[node] = make_float4(al[4], al[5], al[6], al[7]);
  } else {  // degree histogram + bucket scatter (this IS the CSR fill)
    int e = (b - 353 - gD) * 256 + tid;
    if (e >= E) return;
    int d = dstv[e];
    float ea = eattr[e];
    int pos = atomicAdd(&deg[d], 1);
    if (pos < CAP) ebuf[(size_t)d * CAP + pos] = make_int2(srcv[e], __float_as_int(ea));
    atomicAdd(&asum[d], ea);
  }
}

// Layer-0 fused: inline edge weights + aggregate x + project 16->256.
// One wave per node; lane = (es, c): es = edge slot (4), c = x column (16).
// Records via SCALAR s_load (4/step); self-loop handled analytically (es==0).
__global__ __launch_bounds__(256) void agg0_kernel(
    const int* __restrict__ deg, const float* __restrict__ asum,
    const int2* __restrict__ ebuf, const float* __restrict__ al_s,
    const float* __restrict__ al_d, const float* __restrict__ wedot,
    const float* __restrict__ x, const float* __restrict__ W0,
    const float* __restrict__ bias, unsigned short* __restrict__ out, int n) {
  int node = blockIdx.x * 4 + (threadIdx.x >> 6);
  if (node >= n) return;
  int lane = threadIdx.x & 63;
  int es = lane >> 4;
  int c = lane & 15;
  int dg = deg[node];
  int cnt = dg < CAP ? dg : CAP;
  float4 ald = ((const float4*)al_d)[node];
  float wd[4];
#pragma unroll
  for (int h = 0; h < 4; h++) wd[h] = wedot[h];

  float Z[4] = {0.f, 0.f, 0.f, 0.f};
  float den[4] = {0.f, 0.f, 0.f, 0.f};

  if (es == 0) {  // self loop: counted once (es-group 0), reduced over es below
    float xself = x[(size_t)node * 16 + c];
    float ev = asum[node] / fmaxf((float)dg, 1.f);
    float4 as4 = ((const float4*)al_s)[node];
#pragma unroll
    for (int h = 0; h < 4; h++) {
      float a = ((const float*)&as4)[h] + ((const float*)&ald)[h] + ev * wd[h];
      a = fmaxf(a, 0.2f * a);
      a = fminf(a, 30.f);
      float wv = __expf(a);
      den[h] += wv;
      Z[h] = fmaf(wv, xself, Z[h]);
    }
  }

  for (int i = 0; i < cnt; i += 4) {
    int base = __builtin_amdgcn_readfirstlane(node * CAP + i);
    int2 r0 = ebuf[base], r1 = ebuf[base + 1], r2 = ebuf[base + 2], r3 = ebuf[base + 3];
    int2 rm = (es == 0) ? r0 : (es == 1) ? r1 : (es == 2) ? r2 : r3;
    bool valid = (i + es) < cnt;
    int src = valid ? rm.x : 0;
    float ev = valid ? __int_as_float(rm.y) : 0.f;
    float xv = x[(size_t)src * 16 + c];
    float4 as4 = ((const float4*)al_s)[src];
#pragma unroll
    for (int h = 0; h < 4; h++) {
      float a = ((const float*)&as4)[h] + ((const float*)&ald)[h] + ev * wd[h];
      a = fmaxf(a, 0.2f * a);
      a = fminf(a, 30.f);
      float wv = __expf(a);
      wv = valid ? wv : 0.f;
      den[h] += wv;
      Z[h] = fmaf(wv, xv, Z[h]);
    }
  }

#pragma unroll
  for (int h = 0; h < 4; h++) {
    Z[h] += __shfl_xor(Z[h], 16, 64);
    Z[h] += __shfl_xor(Z[h], 32, 64);
    den[h] += __shfl_xor(den[h], 16, 64);
    den[h] += __shfl_xor(den[h], 32, 64);
  }
  int h = es;
  float zsel = (h == 0) ? Z[0] : (h == 1) ? Z[1] : (h == 2) ? Z[2] : Z[3];
  float dsel = (h == 0) ? den[0] : (h == 1) ? den[1] : (h == 2) ? den[2] : den[3];
  float zn = zsel / (dsel + 1e-16f);
  float4 w0r[16];
#pragma unroll
  for (int cc = 0; cc < 16; cc++) w0r[cc] = ((const float4*)(W0 + (size_t)cc * 256))[lane];
  float zc[16];
  int basel = lane & 48;
#pragma unroll
  for (int cc = 0; cc < 16; cc++) zc[cc] = __shfl(zn, basel + cc, 64);
  float o[4];
  float4 b4 = ((const float4*)bias)[lane];
#pragma unroll
  for (int jj = 0; jj < 4; jj++) o[jj] = ((const float*)&b4)[jj];
#pragma unroll
  for (int cc = 0; cc < 16; cc++) {
#pragma unroll
    for (int jj = 0; jj < 4; jj++) o[jj] = fmaf(zc[cc], ((const float*)&w0r[cc])[jj], o[jj]);
  }
  ushort4 o4;
  float ox = o[0] > 0.f ? o[0] : expm1f(o[0]);
  float oy = o[1] > 0.f ? o[1] : expm1f(o[1]);
  float oz = o[2] > 0.f ? o[2] : expm1f(o[2]);
  float ow = o[3] > 0.f ? o[3] : expm1f(o[3]);
  o4.x = f2bf(ox);
  o4.y = f2bf(oy);
  o4.z = f2bf(oz);
  o4.w = f2bf(ow);
  ((ushort4*)out)[(size_t)node * 64 + lane] = o4;
}

// bf16 MFMA GEMM (K=256): bf16 out; al_s/al_d from the extra va col-tile.
template <int M, int H>
__global__ __launch_bounds__(64) void mfma_gemm_dots(
    const unsigned short* __restrict__ Abf, const unsigned short* __restrict__ Wfrag,
    unsigned short* __restrict__ out, float* __restrict__ al_s, float* __restrict__ al_d,
    int n) {
  int lane = threadIdx.x;
  int row0 = blockIdx.x * 16;
  int m = lane & 15, q = lane >> 4;

  short8 afrag[8];
  int r = row0 + m;
  if (r < n) {
    const short8* arow = (const short8*)(Abf + (size_t)r * 256);
#pragma unroll
    for (int ks = 0; ks < 8; ks++) afrag[ks] = arow[ks * 4 + q];
  } else {
#pragma unroll
    for (int ks = 0; ks < 8; ks++) afrag[ks] = (short8)0;
  }

  const short8* wf = (const short8*)Wfrag;

  auto epi = [&](int tile, float4v acc) {
    int col = tile * 16 + m;
#pragma unroll
    for (int reg = 0; reg < 4; reg++) {
      int rr = row0 + q * 4 + reg;
      if (rr < n) out[(size_t)rr * M + col] = f2bf(acc[reg]);
    }
  };

  for (int nt = 0; nt < M / 16; nt += 2) {
    const short8* b0 = wf + (size_t)nt * 8 * 64 + lane;
    const short8* b1 = b0 + 8 * 64;
    short8 bf0[8], bf1[8];
#pragma unroll
    for (int ks = 0; ks < 8; ks++) {
      bf0[ks] = b0[ks * 64];
      bf1[ks] = b1[ks * 64];
    }
    float4v acc0 = {0.f, 0.f, 0.f, 0.f};
    float4v acc1 = {0.f, 0.f, 0.f, 0.f};
#pragma unroll
    for (int ks = 0; ks < 8; ks++) {
      acc0 = __builtin_amdgcn_mfma_f32_16x16x32_bf16(afrag[ks], bf0[ks], acc0, 0, 0, 0);
      acc1 = __builtin_amdgcn_mfma_f32_16x16x32_bf16(afrag[ks], bf1[ks], acc1, 0, 0, 0);
    }
    epi(nt, acc0);
    epi(nt + 1, acc1);
  }

  {
    const short8* bl = wf + (size_t)(M / 16) * 8 * 64 + lane;
    short8 bf[8];
#pragma unroll
    for (int ks = 0; ks < 8; ks++) bf[ks] = bl[ks * 64];
    float4v acc = {0.f, 0.f, 0.f, 0.f};
#pragma unroll
    for (int ks = 0; ks < 8; ks++)
      acc = __builtin_amdgcn_mfma_f32_16x16x32_bf16(afrag[ks], bf[ks], acc, 0, 0, 0);
#pragma unroll
    for (int reg = 0; reg < 4; reg++) {
      int rr = row0 + q * 4 + reg;
      if (rr < n) {
        if (m < H) al_s[(size_t)rr * H + m] = acc[reg];
        else if (m < 2 * H) al_d[(size_t)rr * H + (m - H)] = acc[reg];
      }
    }
  }
}

// H=4 aggregation with inline edge weights: one wave per node; records via
// SCALAR s_load (4/step); halves process interleaved edges (half0: e0,e2 ;
// half1: e1,e3). Self-loop analytic (half==0). Merge via shfl_xor(32).
__global__ __launch_bounds__(256) void agg4_kernel(
    const int* __restrict__ deg, const float* __restrict__ asum,
    const int2* __restrict__ ebuf, const float* __restrict__ al_s,
    const float* __restrict__ al_d, const float* __restrict__ wedot,
    const unsigned short* __restrict__ B, const float* __restrict__ bias,
    unsigned short* __restrict__ out, int n) {
  int node = blockIdx.x * 4 + (threadIdx.x >> 6);
  if (node >= n) return;
  int lane = threadIdx.x & 63;
  int half = lane >> 5;
  int l = lane & 31;
  int h4 = l >> 3;
  int dg = deg[node];
  int cnt = dg < CAP ? dg : CAP;
  float aldh = al_d[(size_t)node * 4 + h4];
  float wdh = wedot[h4];

  float acc[8];
#pragma unroll
  for (int j = 0; j < 8; j++) acc[j] = 0.f;
  float den = 0.f;

  if (half == 0) {  // self loop, counted once (merged via shfl_xor(32))
    float ev = asum[node] / fmaxf((float)dg, 1.f);
    float a = al_s[(size_t)node * 4 + h4] + aldh + ev * wdh;
    a = fmaxf(a, 0.2f * a);
    a = fminf(a, 30.f);
    float wv = __expf(a);
    short8 rowS = ((const short8*)(B + (size_t)node * 256))[l];
    const unsigned short* ps = (const unsigned short*)&rowS;
    den += wv;
#pragma unroll
    for (int j = 0; j < 8; j++) acc[j] = fmaf(wv, bf2f(ps[j]), acc[j]);
  }

  for (int i = 0; i < cnt; i += 4) {
    int base = __builtin_amdgcn_readfirstlane(node * CAP + i);
    int2 r0 = ebuf[base], r1 = ebuf[base + 1], r2 = ebuf[base + 2], r3 = ebuf[base + 3];
    bool vA = (i + (half ? 1 : 0)) < cnt;
    bool vB = (i + (half ? 3 : 2)) < cnt;
    int2 rA = half ? r1 : r0;
    int2 rB = half ? r3 : r2;
    int srcA = vA ? rA.x : 0;
    int srcB = vB ? rB.x : 0;
    float evA = vA ? __int_as_float(rA.y) : 0.f;
    float evB = vB ? __int_as_float(rB.y) : 0.f;
    float aA = al_s[(size_t)srcA * 4 + h4] + aldh + evA * wdh;
    float aB = al_s[(size_t)srcB * 4 + h4] + aldh + evB * wdh;
    aA = fmaxf(aA, 0.2f * aA);
    aB = fmaxf(aB, 0.2f * aB);
    aA = fminf(aA, 30.f);
    aB = fminf(aB, 30.f);
    float wA = __expf(aA);
    float wB = __expf(aB);
    wA = vA ? wA : 0.f;
    wB = vB ? wB : 0.f;
    short8 rowA = ((const short8*)(B + (size_t)srcA * 256))[l];
    short8 rowB = ((const short8*)(B + (size_t)srcB * 256))[l];
    den += wA + wB;
    const unsigned short* pa = (const unsigned short*)&rowA;
    const unsigned short* pb = (const unsigned short*)&rowB;
#pragma unroll
    for (int j = 0; j < 8; j++) acc[j] = fmaf(wA, bf2f(pa[j]), acc[j]);
#pragma unroll
    for (int j = 0; j < 8; j++) acc[j] = fmaf(wB, bf2f(pb[j]), acc[j]);
  }

  den += __shfl_xor(den, 32, 64);
#pragma unroll
  for (int j = 0; j < 8; j++) acc[j] += __shfl_xor(acc[j], 32, 64);

  if (half == 0) {
    float inv = 1.f / (den + 1e-16f);
    float4 b0 = ((const float4*)bias)[l * 2];
    float4 b1 = ((const float4*)bias)[l * 2 + 1];
    unsigned short o8[8];
#pragma unroll
    for (int j = 0; j < 8; j++) {
      float bjv = (j < 4) ? ((const float*)&b0)[j] : ((const float*)&b1)[j - 4];
      float o = acc[j] * inv + bjv;
      o = o > 0.f ? o : expm1f(o);
      o8[j] = f2bf(o);
    }
    ((short8*)(out + (size_t)node * 256))[l] = *(short8*)o8;
  }
}

// H=1 aggregation + inline weights + bias + LayerNorm: one wave per node;
// quad q takes edge q; records via SCALAR s_load; self-loop analytic (q==0).
__global__ __launch_bounds__(256) void agg_ln_kernel(
    const int* __restrict__ deg, const float* __restrict__ asum,
    const int2* __restrict__ ebuf, const float* __restrict__ al_s,
    const float* __restrict__ al_d, const float* __restrict__ wedot,
    const unsigned short* __restrict__ B, const float* __restrict__ bias,
    const float* __restrict__ ln_g, const float* __restrict__ ln_b,
    float* __restrict__ out, int n) {
  int node = blockIdx.x * 4 + (threadIdx.x >> 6);
  if (node >= n) return;
  int lane = threadIdx.x & 63;
  int q = lane >> 4;
  int l = lane & 15;
  int dg = deg[node];
  int cnt = dg < CAP ? dg : CAP;
  float ald = al_d[node];
  float wd = wedot[0];

  float4 acc = make_float4(0.f, 0.f, 0.f, 0.f);
  float den = 0.f;

  if (q == 0) {  // self loop, counted once (reduced over q below)
    float ev = asum[node] / fmaxf((float)dg, 1.f);
    float a = al_s[node] + ald + ev * wd;
    a = fmaxf(a, 0.2f * a);
    a = fminf(a, 30.f);
    float wv = __expf(a);
    ushort4 bv = ((const ushort4*)(B + (size_t)node * 64))[l];
    den += wv;
    acc.x = fmaf(wv, bf2f(bv.x), acc.x);
    acc.y = fmaf(wv, bf2f(bv.y), acc.y);
    acc.z = fmaf(wv, bf2f(bv.z), acc.z);
    acc.w = fmaf(wv, bf2f(bv.w), acc.w);
  }

  for (int i = 0; i < cnt; i += 4) {
    int base = __builtin_amdgcn_readfirstlane(node * CAP + i);
    int2 r0 = ebuf[base], r1 = ebuf[base + 1], r2 = ebuf[base + 2], r3 = ebuf[base + 3];
    int2 rm = (q == 0) ? r0 : (q == 1) ? r1 : (q == 2) ? r2 : r3;
    bool valid = (i + q) < cnt;
    int src = valid ? rm.x : 0;
    float ev = valid ? __int_as_float(rm.y) : 0.f;
    float a = al_s[src] + ald + ev * wd;
    a = fmaxf(a, 0.2f * a);
    a = fminf(a, 30.f);
    float wv = __expf(a);
    wv = valid ? wv : 0.f;
    ushort4 bv = ((const ushort4*)(B + (size_t)src * 64))[l];
    den += wv;
    acc.x = fmaf(wv, bf2f(bv.x), acc.x);
    acc.y = fmaf(wv, bf2f(bv.y), acc.y);
    acc.z = fmaf(wv, bf2f(bv.z), acc.z);
    acc.w = fmaf(wv, bf2f(bv.w), acc.w);
  }

  den += __shfl_xor(den, 32, 64);
  den += __shfl_xor(den, 16, 64);
  acc.x += __shfl_xor(acc.x, 32, 64);
  acc.y += __shfl_xor(acc.y, 32, 64);
  acc.z += __shfl_xor(acc.z, 32, 64);
  acc.w += __shfl_xor(acc.w, 32, 64);
  acc.x += __shfl_xor(acc.x, 16, 64);
  acc.y += __shfl_xor(acc.y, 16, 64);
  acc.z += __shfl_xor(acc.z, 16, 64);
  acc.w += __shfl_xor(acc.w, 16, 64);

  float inv = 1.f / (den + 1e-16f);
  float4 b4 = ((const float4*)bias)[l];
  float4 o;
  o.x = acc.x * inv + b4.x;
  o.y = acc.y * inv + b4.y;
  o.z = acc.z * inv + b4.z;
  o.w = acc.w * inv + b4.w;
  float s = (o.x + o.y) + (o.z + o.w);
#pragma unroll
  for (int off = 1; off < 16; off <<= 1) s += __shfl_xor(s, off, 64);
  float mu = s * (1.f / 64.f);
  float dx = o.x - mu, dy = o.y - mu, dz = o.z - mu, dw = o.w - mu;
  float v = (dx * dx + dy * dy) + (dz * dz + dw * dw);
#pragma unroll
  for (int off = 1; off < 16; off <<= 1) v += __shfl_xor(v, off, 64);
  float rs = rsqrtf(v * (1.f / 64.f) + 1e-5f);
  if (q == 0) {
    float4 g4 = ((const float4*)ln_g)[l];
    float4 lb4 = ((const float4*)ln_b)[l];
    float4 rr;
    rr.x = dx * rs * g4.x + lb4.x;
    rr.y = dy * rs * g4.y + lb4.y;
    rr.z = dz * rs * g4.z + lb4.z;
    rr.w = dw * rs * g4.w + lb4.w;
    ((float4*)(out + (size_t)node * 64))[l] = rr;
  }
}

extern "C" void kernel_launch(void* const* d_in, const int* in_sizes, int n_in,
                              void* d_out, int out_size, void* d_ws, size_t ws_size,
                              hipStream_t stream) {
  const float* x = (const float*)d_in[0];
  const int* ei = (const int*)d_in[1];
  const float* eattr = (const float*)d_in[2];
  const float* W0 = (const float*)d_in[3];
  const float* as0 = (const float*)d_in[4];
  const float* ad0 = (const float*)d_in[5];
  const float* We0 = (const float*)d_in[6];
  const float* ae0 = (const float*)d_in[7];
  const float* b0 = (const float*)d_in[8];
  const float* W1 = (const float*)d_in[9];
  const float* as1 = (const float*)d_in[10];
  const float* ad1 = (const float*)d_in[11];
  const float* We1 = (const float*)d_in[12];
  const float* ae1 = (const float*)d_in[13];
  const float* b1 = (const float*)d_in[14];
  const float* W2 = (const float*)d_in[15];
  const float* as2 = (const float*)d_in[16];
  const float* ad2 = (const float*)d_in[17];
  const float* We2 = (const float*)d_in[18];
  const float* ae2 = (const float*)d_in[19];
  const float* b2 = (const float*)d_in[20];
  const float* lng = (const float*)d_in[21];
  const float* lnb = (const float*)d_in[22];
  float* outp = (float*)d_out;

  const int N = in_sizes[0] / 16;
  const int E = in_sizes[1] / 2;
  const int* srcv = ei;
  const int* dstv = ei + E;

  char* w = (char*)d_ws;
  size_t off = 0;
  auto alloc = [&](size_t bytes) -> void* {
    void* p = w + off;
    off += (bytes + 255) & ~(size_t)255;
    return p;
  };
  int* deg = (int*)alloc((size_t)N * 4);
  float* asum = (float*)alloc((size_t)N * 4);
  size_t zero_bytes = off;  // deg + asum must start at 0
  int2* ebuf = (int2*)alloc(((size_t)N * CAP + 8) * 8);  // +8: s_load overread pad
  float* wedot = (float*)alloc(16 * 4);
  float* al_s = (float*)alloc((size_t)N * 4 * 4);
  float* al_d = (float*)alloc((size_t)N * 4 * 4);
  unsigned short* Wf1 = (unsigned short*)alloc((size_t)17 * 4096 * 2);
  unsigned short* Wf2 = (unsigned short*)alloc((size_t)5 * 4096 * 2);
  unsigned short* bufA = (unsigned short*)alloc((size_t)N * 256 * 2);
  unsigned short* bufB = (unsigned short*)alloc((size_t)N * 256 * 2);
  (void)ws_size;

  hipMemsetAsync(d_ws, 0, zero_bytes, stream);

  int gE = (E + 255) / 256;
  int gD = (N + 255) / 256;

  k1_kernel<<<353 + gD + gE, 256, 0, stream>>>(
      x, srcv, dstv, eattr, W0, as0, ad0, We0, ae0, W1, as1, ad1, We1, ae1,
      W2, as2, ad2, We2, ae2, Wf1, Wf2, wedot, al_s, al_d, deg, asum, ebuf, N, E, gD);

  int gStrip = (N + 15) / 16;
  int gNode4 = (N + 3) / 4;

  // ---- layer 0: fused inline-weights aggregate + project
  agg0_kernel<<<gNode4, 256, 0, stream>>>(deg, asum, ebuf, al_s, al_d, wedot, x, W0, b0,
                                          bufA, N);

  // ---- layer 1
  mfma_gemm_dots<256, 4><<<gStrip, 64, 0, stream>>>(bufA, Wf1, bufB, al_s, al_d, N);
  agg4_kernel<<<gNode4, 256, 0, stream>>>(deg, asum, ebuf, al_s, al_d, wedot + 4, bufB, b1,
                                          bufA, N);

  // ---- layer 2 (+ LayerNorm -> d_out)
  mfma_gemm_dots<64, 1><<<gStrip, 64, 0, stream>>>(bufA, Wf2, bufB, al_s, al_d, N);
  agg_ln_kernel<<<gNode4, 256, 0, stream>>>(deg, asum, ebuf, al_s, al_d, wedot + 8, bufB, b2,
                                            lng, lnb, outp, N);
}

// Round 2
// 215.065 us; speedup vs baseline: 1.3401x; 1.0841x over previous
//
#include <hip/hip_runtime.h>
#include <hip/hip_bf16.h>
#include <math.h>

// GAT x3 + LayerNorm for MI355X (gfx950).
// R13: asum (mean edge-attr) atomics ELIMINATED from k1 -> the agg kernels
// already touch every bucket record, so they accumulate easum alongside den,
// reduce it in the same shuffle tree, and apply the analytic self-loop AFTER
// the reduction (order-independent sums; deg==0 -> mean 0, matching ref).
// k1's edge section now issues ONE device atomic per edge (pos) instead of
// two. Self rows (x[node] / B[node]) are loaded at kernel top so the
// post-reduction self-add has no serial latency tail.
// Carried (R12): bucketed scatter CSR (CAP=64) inside k1, inline softmax
// weights in aggs, 6 dispatches, bf16 h, al = A @ va via extra MFMA col-tile,
// layer-0 aggregate-then-project, scalar-path (s_load) edge-record reads.

typedef __attribute__((ext_vector_type(8))) short short8;
typedef __attribute__((ext_vector_type(4))) float float4v;

#define CAP 64

__device__ __forceinline__ float wave_sum(float v) {
#pragma unroll
  for (int off = 32; off > 0; off >>= 1) v += __shfl_xor(v, off, 64);
  return v;
}

__device__ __forceinline__ unsigned short f2bf(float v) {
  unsigned u = __float_as_uint(v);
  unsigned r = u + 0x7fff + ((u >> 16) & 1);  // RNE
  return (unsigned short)(r >> 16);
}

__device__ __forceinline__ float bf2f(unsigned short u) {
  return __uint_as_float(((unsigned)u) << 16);
}

// ---------------- K1 mega-dispatch ----------------
// blocks [0,272): Wf1 tiles; [272,352): Wf2 tiles; 352: wedot;
// [353,353+gD): layer-0 al dots; rest: degree count + bucket scatter.
__global__ __launch_bounds__(256) void k1_kernel(
    const float* __restrict__ x, const int* __restrict__ srcv, const int* __restrict__ dstv,
    const float* __restrict__ eattr,
    const float* __restrict__ W0, const float* __restrict__ as0, const float* __restrict__ ad0,
    const float* __restrict__ We0, const float* __restrict__ ae0,
    const float* __restrict__ W1, const float* __restrict__ as1, const float* __restrict__ ad1,
    const float* __restrict__ We1, const float* __restrict__ ae1,
    const float* __restrict__ W2, const float* __restrict__ as2, const float* __restrict__ ad2,
    const float* __restrict__ We2, const float* __restrict__ ae2,
    unsigned short* __restrict__ Wf1, unsigned short* __restrict__ Wf2,
    float* __restrict__ wedot, float* __restrict__ al_s, float* __restrict__ al_d,
    int* __restrict__ deg, int2* __restrict__ ebuf,
    int N, int E, int gD) {
  int b = blockIdx.x;
  int tid = threadIdx.x;
  if (b < 272) {  // Wf1: 16 W1-tiles + 1 va1 tile, bf16 fragment order
    int idx = b * 256 + tid;
    int j = idx & 7, lane = (idx >> 3) & 63, ks = (idx >> 9) & 7, nt = idx >> 12;
    int k = ks * 32 + (lane >> 4) * 8 + j;
    int col = lane & 15;
    float v = 0.f;
    if (nt < 16) {
      v = W1[(size_t)k * 256 + nt * 16 + col];
    } else if (col < 4) {
      for (int c = 0; c < 64; c++) v = fmaf(W1[(size_t)k * 256 + col * 64 + c], as1[col * 64 + c], v);
    } else if (col < 8) {
      int h = col - 4;
      for (int c = 0; c < 64; c++) v = fmaf(W1[(size_t)k * 256 + h * 64 + c], ad1[h * 64 + c], v);
    }
    Wf1[idx] = f2bf(v);
  } else if (b < 352) {  // Wf2: 4 W2-tiles + 1 va2 tile
    int idx = (b - 272) * 256 + tid;
    int j = idx & 7, lane = (idx >> 3) & 63, ks = (idx >> 9) & 7, nt = idx >> 12;
    int k = ks * 32 + (lane >> 4) * 8 + j;
    int col = lane & 15;
    float v = 0.f;
    if (nt < 4) {
      v = W2[(size_t)k * 64 + nt * 16 + col];
    } else if (col < 1) {
      for (int c = 0; c < 64; c++) v = fmaf(W2[(size_t)k * 64 + c], as2[c], v);
    } else if (col < 2) {
      for (int c = 0; c < 64; c++) v = fmaf(W2[(size_t)k * 64 + c], ad2[c], v);
    }
    Wf2[idx] = f2bf(v);
  } else if (b == 352) {  // wedot
    if (tid >= 64) return;
    int c = tid;
    for (int h = 0; h < 4; h++) {
      float v = wave_sum(We0[h * 64 + c] * ae0[h * 64 + c]);
      if (c == 0) wedot[h] = v;
    }
    for (int h = 0; h < 4; h++) {
      float v = wave_sum(We1[h * 64 + c] * ae1[h * 64 + c]);
      if (c == 0) wedot[4 + h] = v;
    }
    float v = wave_sum(We2[c] * ae2[c]);
    if (c == 0) wedot[8] = v;
  } else if (b < 353 + gD) {  // layer-0 dots: al = x @ va0
    __shared__ float va[128];
    if (tid < 128) {
      int k = tid >> 3, col = tid & 7;
      float v = 0.f;
      if (col < 4) {
        for (int c = 0; c < 64; c++) v = fmaf(W0[(size_t)k * 256 + col * 64 + c], as0[col * 64 + c], v);
      } else {
        int h = col - 4;
        for (int c = 0; c < 64; c++) v = fmaf(W0[(size_t)k * 256 + h * 64 + c], ad0[h * 64 + c], v);
      }
      va[tid] = v;
    }
    __syncthreads();
    int node = (b - 353) * 256 + tid;
    if (node >= N) return;
    const float4* xr = (const float4*)(x + (size_t)node * 16);
    float4 xv[4];
#pragma unroll
    for (int q = 0; q < 4; q++) xv[q] = xr[q];
    float al[8];
#pragma unroll
    for (int j = 0; j < 8; j++) al[j] = 0.f;
#pragma unroll
    for (int k = 0; k < 16; k++) {
      float xk = ((const float*)xv)[k];
#pragma unroll
      for (int j = 0; j < 8; j++) al[j] = fmaf(xk, va[k * 8 + j], al[j]);
    }
    ((float4*)al_s)[node] = make_float4(al[0], al[1], al[2], al[3]);
    ((float4*)al_d)[node] = make_float4(al[4], al[5], al[6], al[7]);
  } else {  // degree count + bucket scatter (this IS the CSR fill)
    int e = (b - 353 - gD) * 256 + tid;
    if (e >= E) return;
    int d = dstv[e];
    int s = srcv[e];
    float ea = eattr[e];
    int pos = atomicAdd(&deg[d], 1);
    if (pos < CAP) ebuf[(size_t)d * CAP + pos] = make_int2(s, __float_as_int(ea));
  }
}

// Layer-0 fused: inline edge weights + aggregate x + project 16->256.
// One wave per node; lane = (es, c): es = edge slot (4), c = x column (16).
// Records via SCALAR s_load (4/step); self-loop applied post-reduction from
// the in-loop easum (mean edge-attr).
__global__ __launch_bounds__(256) void agg0_kernel(
    const int* __restrict__ deg, const int2* __restrict__ ebuf,
    const float* __restrict__ al_s, const float* __restrict__ al_d,
    const float* __restrict__ wedot,
    const float* __restrict__ x, const float* __restrict__ W0,
    const float* __restrict__ bias, unsigned short* __restrict__ out, int n) {
  int node = blockIdx.x * 4 + (threadIdx.x >> 6);
  if (node >= n) return;
  int lane = threadIdx.x & 63;
  int es = lane >> 4;
  int c = lane & 15;
  int dg = deg[node];
  int cnt = dg < CAP ? dg : CAP;
  // self-row operands hoisted (independent of the loop)
  float xself = x[(size_t)node * 16 + c];
  float4 as4s = ((const float4*)al_s)[node];
  float4 ald = ((const float4*)al_d)[node];
  float wd[4];
#pragma unroll
  for (int h = 0; h < 4; h++) wd[h] = wedot[h];

  float Z[4] = {0.f, 0.f, 0.f, 0.f};
  float den[4] = {0.f, 0.f, 0.f, 0.f};
  float easum = 0.f;

  for (int i = 0; i < cnt; i += 4) {
    int base = __builtin_amdgcn_readfirstlane(node * CAP + i);
    int2 r0 = ebuf[base], r1 = ebuf[base + 1], r2 = ebuf[base + 2], r3 = ebuf[base + 3];
    int2 rm = (es == 0) ? r0 : (es == 1) ? r1 : (es == 2) ? r2 : r3;
    bool valid = (i + es) < cnt;
    int src = valid ? rm.x : 0;
    float ev = valid ? __int_as_float(rm.y) : 0.f;
    float xv = x[(size_t)src * 16 + c];
    float4 as4 = ((const float4*)al_s)[src];
    easum += ev;
#pragma unroll
    for (int h = 0; h < 4; h++) {
      float a = ((const float*)&as4)[h] + ((const float*)&ald)[h] + ev * wd[h];
      a = fmaxf(a, 0.2f * a);
      a = fminf(a, 30.f);
      float wv = __expf(a);
      wv = valid ? wv : 0.f;
      den[h] += wv;
      Z[h] = fmaf(wv, xv, Z[h]);
    }
  }

#pragma unroll
  for (int h = 0; h < 4; h++) {
    Z[h] += __shfl_xor(Z[h], 16, 64);
    Z[h] += __shfl_xor(Z[h], 32, 64);
    den[h] += __shfl_xor(den[h], 16, 64);
    den[h] += __shfl_xor(den[h], 32, 64);
  }
  easum += __shfl_xor(easum, 16, 64);
  easum += __shfl_xor(easum, 32, 64);

  // self loop: every lane adds its own column's contribution (post-reduce)
  {
    float evs = easum / fmaxf((float)dg, 1.f);
#pragma unroll
    for (int h = 0; h < 4; h++) {
      float a = ((const float*)&as4s)[h] + ((const float*)&ald)[h] + evs * wd[h];
      a = fmaxf(a, 0.2f * a);
      a = fminf(a, 30.f);
      float wv = __expf(a);
      den[h] += wv;
      Z[h] = fmaf(wv, xself, Z[h]);
    }
  }

  int h = es;
  float zsel = (h == 0) ? Z[0] : (h == 1) ? Z[1] : (h == 2) ? Z[2] : Z[3];
  float dsel = (h == 0) ? den[0] : (h == 1) ? den[1] : (h == 2) ? den[2] : den[3];
  float zn = zsel / (dsel + 1e-16f);
  float4 w0r[16];
#pragma unroll
  for (int cc = 0; cc < 16; cc++) w0r[cc] = ((const float4*)(W0 + (size_t)cc * 256))[lane];
  float zc[16];
  int basel = lane & 48;
#pragma unroll
  for (int cc = 0; cc < 16; cc++) zc[cc] = __shfl(zn, basel + cc, 64);
  float o[4];
  float4 b4 = ((const float4*)bias)[lane];
#pragma unroll
  for (int jj = 0; jj < 4; jj++) o[jj] = ((const float*)&b4)[jj];
#pragma unroll
  for (int cc = 0; cc < 16; cc++) {
#pragma unroll
    for (int jj = 0; jj < 4; jj++) o[jj] = fmaf(zc[cc], ((const float*)&w0r[cc])[jj], o[jj]);
  }
  ushort4 o4;
  float ox = o[0] > 0.f ? o[0] : expm1f(o[0]);
  float oy = o[1] > 0.f ? o[1] : expm1f(o[1]);
  float oz = o[2] > 0.f ? o[2] : expm1f(o[2]);
  float ow = o[3] > 0.f ? o[3] : expm1f(o[3]);
  o4.x = f2bf(ox);
  o4.y = f2bf(oy);
  o4.z = f2bf(oz);
  o4.w = f2bf(ow);
  ((ushort4*)out)[(size_t)node * 64 + lane] = o4;
}

// bf16 MFMA GEMM (K=256): bf16 out; al_s/al_d from the extra va col-tile.
template <int M, int H>
__global__ __launch_bounds__(64) void mfma_gemm_dots(
    const unsigned short* __restrict__ Abf, const unsigned short* __restrict__ Wfrag,
    unsigned short* __restrict__ out, float* __restrict__ al_s, float* __restrict__ al_d,
    int n) {
  int lane = threadIdx.x;
  int row0 = blockIdx.x * 16;
  int m = lane & 15, q = lane >> 4;

  short8 afrag[8];
  int r = row0 + m;
  if (r < n) {
    const short8* arow = (const short8*)(Abf + (size_t)r * 256);
#pragma unroll
    for (int ks = 0; ks < 8; ks++) afrag[ks] = arow[ks * 4 + q];
  } else {
#pragma unroll
    for (int ks = 0; ks < 8; ks++) afrag[ks] = (short8)0;
  }

  const short8* wf = (const short8*)Wfrag;

  auto epi = [&](int tile, float4v acc) {
    int col = tile * 16 + m;
#pragma unroll
    for (int reg = 0; reg < 4; reg++) {
      int rr = row0 + q * 4 + reg;
      if (rr < n) out[(size_t)rr * M + col] = f2bf(acc[reg]);
    }
  };

  for (int nt = 0; nt < M / 16; nt += 2) {
    const short8* b0 = wf + (size_t)nt * 8 * 64 + lane;
    const short8* b1 = b0 + 8 * 64;
    short8 bf0[8], bf1[8];
#pragma unroll
    for (int ks = 0; ks < 8; ks++) {
      bf0[ks] = b0[ks * 64];
      bf1[ks] = b1[ks * 64];
    }
    float4v acc0 = {0.f, 0.f, 0.f, 0.f};
    float4v acc1 = {0.f, 0.f, 0.f, 0.f};
#pragma unroll
    for (int ks = 0; ks < 8; ks++) {
      acc0 = __builtin_amdgcn_mfma_f32_16x16x32_bf16(afrag[ks], bf0[ks], acc0, 0, 0, 0);
      acc1 = __builtin_amdgcn_mfma_f32_16x16x32_bf16(afrag[ks], bf1[ks], acc1, 0, 0, 0);
    }
    epi(nt, acc0);
    epi(nt + 1, acc1);
  }

  {
    const short8* bl = wf + (size_t)(M / 16) * 8 * 64 + lane;
    short8 bf[8];
#pragma unroll
    for (int ks = 0; ks < 8; ks++) bf[ks] = bl[ks * 64];
    float4v acc = {0.f, 0.f, 0.f, 0.f};
#pragma unroll
    for (int ks = 0; ks < 8; ks++)
      acc = __builtin_amdgcn_mfma_f32_16x16x32_bf16(afrag[ks], bf[ks], acc, 0, 0, 0);
#pragma unroll
    for (int reg = 0; reg < 4; reg++) {
      int rr = row0 + q * 4 + reg;
      if (rr < n) {
        if (m < H) al_s[(size_t)rr * H + m] = acc[reg];
        else if (m < 2 * H) al_d[(size_t)rr * H + (m - H)] = acc[reg];
      }
    }
  }
}

// H=4 aggregation with inline edge weights: one wave per node; records via
// SCALAR s_load (4/step); halves process interleaved edges (half0: e0,e2 ;
// half1: e1,e3). Self-loop applied post-reduction from in-loop easum.
__global__ __launch_bounds__(256) void agg4_kernel(
    const int* __restrict__ deg, const int2* __restrict__ ebuf,
    const float* __restrict__ al_s, const float* __restrict__ al_d,
    const float* __restrict__ wedot,
    const unsigned short* __restrict__ B, const float* __restrict__ bias,
    unsigned short* __restrict__ out, int n) {
  int node = blockIdx.x * 4 + (threadIdx.x >> 6);
  if (node >= n) return;
  int lane = threadIdx.x & 63;
  int half = lane >> 5;
  int l = lane & 31;
  int h4 = l >> 3;
  int dg = deg[node];
  int cnt = dg < CAP ? dg : CAP;
  float aldh = al_d[(size_t)node * 4 + h4];
  float alsh = al_s[(size_t)node * 4 + h4];
  float wdh = wedot[h4];
  // self row hoisted (address known up front)
  short8 rowS = ((const short8*)(B + (size_t)node * 256))[l];

  float acc[8];
#pragma unroll
  for (int j = 0; j < 8; j++) acc[j] = 0.f;
  float den = 0.f;
  float easum = 0.f;

  for (int i = 0; i < cnt; i += 4) {
    int base = __builtin_amdgcn_readfirstlane(node * CAP + i);
    int2 r0 = ebuf[base], r1 = ebuf[base + 1], r2 = ebuf[base + 2], r3 = ebuf[base + 3];
    bool vA = (i + (half ? 1 : 0)) < cnt;
    bool vB = (i + (half ? 3 : 2)) < cnt;
    int2 rA = half ? r1 : r0;
    int2 rB = half ? r3 : r2;
    int srcA = vA ? rA.x : 0;
    int srcB = vB ? rB.x : 0;
    float evA = vA ? __int_as_float(rA.y) : 0.f;
    float evB = vB ? __int_as_float(rB.y) : 0.f;
    easum += evA + evB;
    float aA = al_s[(size_t)srcA * 4 + h4] + aldh + evA * wdh;
    float aB = al_s[(size_t)srcB * 4 + h4] + aldh + evB * wdh;
    aA = fmaxf(aA, 0.2f * aA);
    aB = fmaxf(aB, 0.2f * aB);
    aA = fminf(aA, 30.f);
    aB = fminf(aB, 30.f);
    float wA = __expf(aA);
    float wB = __expf(aB);
    wA = vA ? wA : 0.f;
    wB = vB ? wB : 0.f;
    short8 rowA = ((const short8*)(B + (size_t)srcA * 256))[l];
    short8 rowB = ((const short8*)(B + (size_t)srcB * 256))[l];
    den += wA + wB;
    const unsigned short* pa = (const unsigned short*)&rowA;
    const unsigned short* pb = (const unsigned short*)&rowB;
#pragma unroll
    for (int j = 0; j < 8; j++) acc[j] = fmaf(wA, bf2f(pa[j]), acc[j]);
#pragma unroll
    for (int j = 0; j < 8; j++) acc[j] = fmaf(wB, bf2f(pb[j]), acc[j]);
  }

  den += __shfl_xor(den, 32, 64);
  easum += __shfl_xor(easum, 32, 64);
#pragma unroll
  for (int j = 0; j < 8; j++) acc[j] += __shfl_xor(acc[j], 32, 64);

  // self loop (post-reduce, uniform across halves; only half 0 writes out)
  {
    float evs = easum / fmaxf((float)dg, 1.f);
    float a = alsh + aldh + evs * wdh;
    a = fmaxf(a, 0.2f * a);
    a = fminf(a, 30.f);
    float wv = __expf(a);
    const unsigned short* ps = (const unsigned short*)&rowS;
    den += wv;
#pragma unroll
    for (int j = 0; j < 8; j++) acc[j] = fmaf(wv, bf2f(ps[j]), acc[j]);
  }

  if (half == 0) {
    float inv = 1.f / (den + 1e-16f);
    float4 b0 = ((const float4*)bias)[l * 2];
    float4 b1 = ((const float4*)bias)[l * 2 + 1];
    unsigned short o8[8];
#pragma unroll
    for (int j = 0; j < 8; j++) {
      float bjv = (j < 4) ? ((const float*)&b0)[j] : ((const float*)&b1)[j - 4];
      float o = acc[j] * inv + bjv;
      o = o > 0.f ? o : expm1f(o);
      o8[j] = f2bf(o);
    }
    ((short8*)(out + (size_t)node * 256))[l] = *(short8*)o8;
  }
}

// H=1 aggregation + inline weights + bias + LayerNorm: one wave per node;
// quad q takes edge q; records via SCALAR s_load; self-loop post-reduction.
__global__ __launch_bounds__(256) void agg_ln_kernel(
    const int* __restrict__ deg, const int2* __restrict__ ebuf,
    const float* __restrict__ al_s, const float* __restrict__ al_d,
    const float* __restrict__ wedot,
    const unsigned short* __restrict__ B, const float* __restrict__ bias,
    const float* __restrict__ ln_g, const float* __restrict__ ln_b,
    float* __restrict__ out, int n) {
  int node = blockIdx.x * 4 + (threadIdx.x >> 6);
  if (node >= n) return;
  int lane = threadIdx.x & 63;
  int q = lane >> 4;
  int l = lane & 15;
  int dg = deg[node];
  int cnt = dg < CAP ? dg : CAP;
  float ald = al_d[node];
  float als = al_s[node];
  float wd = wedot[0];
  // self row hoisted
  ushort4 bvS = ((const ushort4*)(B + (size_t)node * 64))[l];

  float4 acc = make_float4(0.f, 0.f, 0.f, 0.f);
  float den = 0.f;
  float easum = 0.f;

  for (int i = 0; i < cnt; i += 4) {
    int base = __builtin_amdgcn_readfirstlane(node * CAP + i);
    int2 r0 = ebuf[base], r1 = ebuf[base + 1], r2 = ebuf[base + 2], r3 = ebuf[base + 3];
    int2 rm = (q == 0) ? r0 : (q == 1) ? r1 : (q == 2) ? r2 : r3;
    bool valid = (i + q) < cnt;
    int src = valid ? rm.x : 0;
    float ev = valid ? __int_as_float(rm.y) : 0.f;
    easum += ev;
    float a = al_s[src] + ald + ev * wd;
    a = fmaxf(a, 0.2f * a);
    a = fminf(a, 30.f);
    float wv = __expf(a);
    wv = valid ? wv : 0.f;
    ushort4 bv = ((const ushort4*)(B + (size_t)src * 64))[l];
    den += wv;
    acc.x = fmaf(wv, bf2f(bv.x), acc.x);
    acc.y = fmaf(wv, bf2f(bv.y), acc.y);
    acc.z = fmaf(wv, bf2f(bv.z), acc.z);
    acc.w = fmaf(wv, bf2f(bv.w), acc.w);
  }

  den += __shfl_xor(den, 32, 64);
  den += __shfl_xor(den, 16, 64);
  easum += __shfl_xor(easum, 32, 64);
  easum += __shfl_xor(easum, 16, 64);
  acc.x += __shfl_xor(acc.x, 32, 64);
  acc.y += __shfl_xor(acc.y, 32, 64);
  acc.z += __shfl_xor(acc.z, 32, 64);
  acc.w += __shfl_xor(acc.w, 32, 64);
  acc.x += __shfl_xor(acc.x, 16, 64);
  acc.y += __shfl_xor(acc.y, 16, 64);
  acc.z += __shfl_xor(acc.z, 16, 64);
  acc.w += __shfl_xor(acc.w, 16, 64);

  // self loop (post-reduce, uniform across q groups; only q==0 writes out)
  {
    float evs = easum / fmaxf((float)dg, 1.f);
    float a = als + ald + evs * wd;
    a = fmaxf(a, 0.2f * a);
    a = fminf(a, 30.f);
    float wv = __expf(a);
    den += wv;
    acc.x = fmaf(wv, bf2f(bvS.x), acc.x);
    acc.y = fmaf(wv, bf2f(bvS.y), acc.y);
    acc.z = fmaf(wv, bf2f(bvS.z), acc.z);
    acc.w = fmaf(wv, bf2f(bvS.w), acc.w);
  }

  float inv = 1.f / (den + 1e-16f);
  float4 b4 = ((const float4*)bias)[l];
  float4 o;
  o.x = acc.x * inv + b4.x;
  o.y = acc.y * inv + b4.y;
  o.z = acc.z * inv + b4.z;
  o.w = acc.w * inv + b4.w;
  float s = (o.x + o.y) + (o.z + o.w);
#pragma unroll
  for (int off = 1; off < 16; off <<= 1) s += __shfl_xor(s, off, 64);
  float mu = s * (1.f / 64.f);
  float dx = o.x - mu, dy = o.y - mu, dz = o.z - mu, dw = o.w - mu;
  float v = (dx * dx + dy * dy) + (dz * dz + dw * dw);
#pragma unroll
  for (int off = 1; off < 16; off <<= 1) v += __shfl_xor(v, off, 64);
  float rs = rsqrtf(v * (1.f / 64.f) + 1e-5f);
  if (q == 0) {
    float4 g4 = ((const float4*)ln_g)[l];
    float4 lb4 = ((const float4*)ln_b)[l];
    float4 rr;
    rr.x = dx * rs * g4.x + lb4.x;
    rr.y = dy * rs * g4.y + lb4.y;
    rr.z = dz * rs * g4.z + lb4.z;
    rr.w = dw * rs * g4.w + lb4.w;
    ((float4*)(out + (size_t)node * 64))[l] = rr;
  }
}

extern "C" void kernel_launch(void* const* d_in, const int* in_sizes, int n_in,
                              void* d_out, int out_size, void* d_ws, size_t ws_size,
                              hipStream_t stream) {
  const float* x = (const float*)d_in[0];
  const int* ei = (const int*)d_in[1];
  const float* eattr = (const float*)d_in[2];
  const float* W0 = (const float*)d_in[3];
  const float* as0 = (const float*)d_in[4];
  const float* ad0 = (const float*)d_in[5];
  const float* We0 = (const float*)d_in[6];
  const float* ae0 = (const float*)d_in[7];
  const float* b0 = (const float*)d_in[8];
  const float* W1 = (const float*)d_in[9];
  const float* as1 = (const float*)d_in[10];
  const float* ad1 = (const float*)d_in[11];
  const float* We1 = (const float*)d_in[12];
  const float* ae1 = (const float*)d_in[13];
  const float* b1 = (const float*)d_in[14];
  const float* W2 = (const float*)d_in[15];
  const float* as2 = (const float*)d_in[16];
  const float* ad2 = (const float*)d_in[17];
  const float* We2 = (const float*)d_in[18];
  const float* ae2 = (const float*)d_in[19];
  const float* b2 = (const float*)d_in[20];
  const float* lng = (const float*)d_in[21];
  const float* lnb = (const float*)d_in[22];
  float* outp = (float*)d_out;

  const int N = in_sizes[0] / 16;
  const int E = in_sizes[1] / 2;
  const int* srcv = ei;
  const int* dstv = ei + E;

  char* w = (char*)d_ws;
  size_t off = 0;
  auto alloc = [&](size_t bytes) -> void* {
    void* p = w + off;
    off += (bytes + 255) & ~(size_t)255;
    return p;
  };
  int* deg = (int*)alloc((size_t)N * 4);
  size_t zero_bytes = off;  // deg must start at 0
  int2* ebuf = (int2*)alloc(((size_t)N * CAP + 8) * 8);  // +8: s_load overread pad
  float* wedot = (float*)alloc(16 * 4);
  float* al_s = (float*)alloc((size_t)N * 4 * 4);
  float* al_d = (float*)alloc((size_t)N * 4 * 4);
  unsigned short* Wf1 = (unsigned short*)alloc((size_t)17 * 4096 * 2);
  unsigned short* Wf2 = (unsigned short*)alloc((size_t)5 * 4096 * 2);
  unsigned short* bufA = (unsigned short*)alloc((size_t)N * 256 * 2);
  unsigned short* bufB = (unsigned short*)alloc((size_t)N * 256 * 2);
  (void)ws_size;

  hipMemsetAsync(d_ws, 0, zero_bytes, stream);

  int gE = (E + 255) / 256;
  int gD = (N + 255) / 256;

  k1_kernel<<<353 + gD + gE, 256, 0, stream>>>(
      x, srcv, dstv, eattr, W0, as0, ad0, We0, ae0, W1, as1, ad1, We1, ae1,
      W2, as2, ad2, We2, ae2, Wf1, Wf2, wedot, al_s, al_d, deg, ebuf, N, E, gD);

  int gStrip = (N + 15) / 16;
  int gNode4 = (N + 3) / 4;

  // ---- layer 0: fused inline-weights aggregate + project
  agg0_kernel<<<gNode4, 256, 0, stream>>>(deg, ebuf, al_s, al_d, wedot, x, W0, b0,
                                          bufA, N);

  // ---- layer 1
  mfma_gemm_dots<256, 4><<<gStrip, 64, 0, stream>>>(bufA, Wf1, bufB, al_s, al_d, N);
  agg4_kernel<<<gNode4, 256, 0, stream>>>(deg, ebuf, al_s, al_d, wedot + 4, bufB, b1,
                                          bufA, N);

  // ---- layer 2 (+ LayerNorm -> d_out)
  mfma_gemm_dots<64, 1><<<gStrip, 64, 0, stream>>>(bufA, Wf2, bufB, al_s, al_d, N);
  agg_ln_kernel<<<gNode4, 256, 0, stream>>>(deg, ebuf, al_s, al_d, wedot + 8, bufB, b2,
                                            lng, lnb, outp, N);
}